// Round 1
// baseline (1617.759 us; speedup 1.0000x reference)
//
#include <hip/hip_runtime.h>

// Fused TemporalAttentionLayer for MI355X (gfx950).
// N=4096 nodes, T=64, D=256, H=16, dh=16. One node per block, 4 waves.
// Wave w owns output columns [64w, 64w+64) == heads 4w..4w+3.

#define LDS_FENCE() asm volatile("s_waitcnt lgkmcnt(0)" ::: "memory")

typedef __attribute__((ext_vector_type(4))) float f32x4;
typedef __attribute__((ext_vector_type(8))) short bf16x8;
typedef __attribute__((ext_vector_type(4))) short bf16x4;

__device__ __forceinline__ unsigned short f2b(float f) {
    union { float f; unsigned u; } v; v.f = f;
    unsigned r = v.u + 0x7fffu + ((v.u >> 16) & 1u);   // RNE
    return (unsigned short)(r >> 16);
}
__device__ __forceinline__ float b2f(unsigned short s) {
    union { unsigned u; float f; } v; v.u = ((unsigned)s) << 16; return v.f;
}

// ---- preprocess: cast fp32 weights [K=256][N=256] to bf16 in MFMA B-frag order.
// Layout: [ntile(16)][kstep(8)][lane(64)][j(8)], element = W[ks*32+(lane>>4)*8+j][nt*16+(lane&15)]
__global__ void swizzle_w_kernel(const float* __restrict__ Wq,
                                 const float* __restrict__ Wk,
                                 const float* __restrict__ Wv,
                                 const float* __restrict__ Wf,
                                 unsigned short* __restrict__ ws) {
    int tid  = blockIdx.x * 256 + threadIdx.x;   // 0..32767
    int mat  = tid >> 13;
    int rem  = tid & 8191;
    int nt   = rem >> 9;
    int ks   = (rem >> 6) & 7;
    int lane = rem & 63;
    const float* W = (mat == 0) ? Wq : (mat == 1) ? Wk : (mat == 2) ? Wv : Wf;
    int n  = nt * 16 + (lane & 15);
    int k0 = ks * 32 + (lane >> 4) * 8;
    bf16x8 o;
    for (int j = 0; j < 8; ++j) o[j] = (short)f2b(W[(k0 + j) * 256 + n]);
    *(bf16x8*)(ws + (size_t)mat * 65536 + (size_t)rem * 8) = o;
}

__global__ __launch_bounds__(256, 2) void fused_node_kernel(
    const float* __restrict__ x, const float* __restrict__ pos,
    const unsigned short* __restrict__ wsw, const float* __restrict__ bff,
    float* __restrict__ out)
{
    __shared__ unsigned short lds_h[64 * 264];        // h, later attn_out (bf16, pad 8)
    __shared__ unsigned short lds_s[4][64 * 72];      // per-wave transpose scratch

    const int tid  = threadIdx.x;
    const int w    = tid >> 6;
    const int lane = tid & 63;
    const int quad = lane >> 4;
    const int lc   = lane & 15;
    const int node = blockIdx.x;

    // ---- stage 1: h = x + pos_emb  -> bf16 LDS
    {
        const float4* xv = (const float4*)(x + (size_t)node * 16384);
        const float4* pv = (const float4*)pos;
        for (int it = 0; it < 16; ++it) {
            int idx = it * 256 + tid;           // 4096 float4 chunks
            float4 a = xv[idx];
            float4 b = pv[idx];
            int row = idx >> 6, c4 = idx & 63;
            ushort4 o;
            o.x = f2b(a.x + b.x); o.y = f2b(a.y + b.y);
            o.z = f2b(a.z + b.z); o.w = f2b(a.w + b.w);
            *(ushort4*)&lds_h[row * 264 + c4 * 4] = o;
        }
    }
    __syncthreads();

    const f32x4 fzero = {0.f, 0.f, 0.f, 0.f};
    f32x4 acc[4][4];
    bf16x4 qf[4][4], kf[4][4], vf[4][4];

    // C = lds_h[64x256] @ W (wave's 64-col chunk). acc[i][jn]: mtile i, local ntile jn.
#define GEMM_H(WOFF)                                                                              \
    do {                                                                                          \
        for (int i = 0; i < 4; ++i) for (int j = 0; j < 4; ++j) acc[i][j] = fzero;                \
        const unsigned short* wb = wsw + (WOFF);                                                  \
        for (int ks = 0; ks < 8; ++ks) {                                                          \
            bf16x8 afr[4];                                                                        \
            for (int i = 0; i < 4; ++i)                                                           \
                afr[i] = *(const bf16x8*)&lds_h[(i * 16 + lc) * 264 + ks * 32 + quad * 8];        \
            for (int jn = 0; jn < 4; ++jn) {                                                      \
                bf16x8 bfr = *(const bf16x8*)&wb[(size_t)(((w * 4 + jn) * 8 + ks) * 64 + lane) * 8]; \
                for (int i = 0; i < 4; ++i)                                                       \
                    acc[i][jn] = __builtin_amdgcn_mfma_f32_16x16x32_bf16(afr[i], bfr, acc[i][jn], 0, 0, 0); \
            }                                                                                     \
        }                                                                                         \
    } while (0)

    // C-layout acc -> per-wave scratch (bf16, stride 72)
#define SPILL_TO_SCRATCH()                                                                        \
    do {                                                                                          \
        LDS_FENCE();                                                                              \
        for (int i = 0; i < 4; ++i)                                                               \
            for (int jn = 0; jn < 4; ++jn)                                                        \
                for (int r = 0; r < 4; ++r)                                                       \
                    lds_s[w][(i * 16 + quad * 4 + r) * 72 + jn * 16 + lc] = f2b(acc[i][jn][r]);   \
        LDS_FENCE();                                                                              \
    } while (0)

    // ---- Q projection -> A-frags (lane: Q[t=lc][dh=quad*4+j])
    GEMM_H(0);
    SPILL_TO_SCRATCH();
    for (int h = 0; h < 4; ++h)
        for (int i = 0; i < 4; ++i)
            qf[h][i] = *(const bf16x4*)&lds_s[w][(i * 16 + lc) * 72 + h * 16 + quad * 4];

    // ---- K projection -> B-frags (lane: K[s=lc][dh=quad*4+j], i.e. K^T)
    GEMM_H(65536);
    SPILL_TO_SCRATCH();
    for (int h = 0; h < 4; ++h)
        for (int js = 0; js < 4; ++js)
            kf[h][js] = *(const bf16x4*)&lds_s[w][(js * 16 + lc) * 72 + h * 16 + quad * 4];

    // ---- V projection: C-layout IS the PV B-frag layout (V[s=quad*4+r][dh=lc]) — pack in regs
    GEMM_H(131072);
    for (int i = 0; i < 4; ++i)
        for (int jn = 0; jn < 4; ++jn) {
            bf16x4 t;
            t[0] = (short)f2b(acc[i][jn][0]);
            t[1] = (short)f2b(acc[i][jn][1]);
            t[2] = (short)f2b(acc[i][jn][2]);
            t[3] = (short)f2b(acc[i][jn][3]);
            vf[jn][i] = t;   // vf[head][stile]
        }

    __syncthreads();   // all lds_h (h) reads done; it now becomes attn_out

    // ---- attention: 4 heads per wave, fully wave-local
    for (int h = 0; h < 4; ++h) {
        // scores S[t][s], tiles [i][js], K=16 single step
        f32x4 s[4][4];
        for (int i = 0; i < 4; ++i)
            for (int js = 0; js < 4; ++js)
                s[i][js] = __builtin_amdgcn_mfma_f32_16x16x16bf16_1k(qf[h][i], kf[h][js], fzero, 0, 0, 0);

        // scale 1/sqrt(T)=0.125, causal mask, row softmax (row lives on the quad's 16 lanes)
        f32x4 rinv[4];
        for (int i = 0; i < 4; ++i)
            for (int r = 0; r < 4; ++r) {
                int trow = i * 16 + quad * 4 + r;
                float mx = -3.0e38f;
                for (int js = 0; js < 4; ++js) {
                    int scol = js * 16 + lc;
                    float v = s[i][js][r] * 0.125f;
                    v = (scol <= trow) ? v : -1.0e30f;
                    s[i][js][r] = v;
                    mx = fmaxf(mx, v);
                }
                for (int m = 1; m < 16; m <<= 1) mx = fmaxf(mx, __shfl_xor(mx, m, 64));
                float sum = 0.0f;
                for (int js = 0; js < 4; ++js) {
                    float p = __expf(s[i][js][r] - mx);
                    s[i][js][r] = p;
                    sum += p;
                }
                for (int m = 1; m < 16; m <<= 1) sum += __shfl_xor(sum, m, 64);
                rinv[i][r] = 1.0f / sum;
            }

        // P (C-layout) -> scratch -> A-frags for PV
        LDS_FENCE();
        for (int i = 0; i < 4; ++i)
            for (int js = 0; js < 4; ++js)
                for (int r = 0; r < 4; ++r)
                    lds_s[w][(i * 16 + quad * 4 + r) * 72 + js * 16 + lc] = f2b(s[i][js][r]);
        LDS_FENCE();

        f32x4 O[4];
        for (int i = 0; i < 4; ++i) {
            O[i] = fzero;
            for (int js = 0; js < 4; ++js) {
                bf16x4 pa = *(const bf16x4*)&lds_s[w][(i * 16 + lc) * 72 + js * 16 + quad * 4];
                O[i] = __builtin_amdgcn_mfma_f32_16x16x16bf16_1k(pa, vf[h][js], O[i], 0, 0, 0);
            }
        }
        // normalize rows (rinv lanes match O's C-layout rows), write attn_out
        for (int i = 0; i < 4; ++i)
            for (int r = 0; r < 4; ++r) {
                float o = O[i][r] * rinv[i][r];
                lds_h[(i * 16 + quad * 4 + r) * 264 + w * 64 + h * 16 + lc] = f2b(o);
            }
    }

    __syncthreads();   // attn_out complete across waves

    // ---- FFN: relu(attn_out @ Wff + b) + attn_out
    GEMM_H(196608);
    {
        float bias[4];
        for (int jn = 0; jn < 4; ++jn) bias[jn] = bff[w * 64 + jn * 16 + lc];
        float* outn = out + (size_t)node * 16384;
        for (int i = 0; i < 4; ++i)
            for (int jn = 0; jn < 4; ++jn)
                for (int r = 0; r < 4; ++r) {
                    int row = i * 16 + quad * 4 + r;
                    int col = w * 64 + jn * 16 + lc;
                    float v = acc[i][jn][r] + bias[jn];
                    v = fmaxf(v, 0.0f);
                    v += b2f(lds_h[row * 264 + col]);
                    outn[row * 256 + col] = v;
                }
    }
#undef GEMM_H
#undef SPILL_TO_SCRATCH
}

extern "C" void kernel_launch(void* const* d_in, const int* in_sizes, int n_in,
                              void* d_out, int out_size, void* d_ws, size_t ws_size,
                              hipStream_t stream) {
    const float* x   = (const float*)d_in[0];
    const float* pos = (const float*)d_in[1];
    const float* Wq  = (const float*)d_in[2];
    const float* Wk  = (const float*)d_in[3];
    const float* Wv  = (const float*)d_in[4];
    const float* Wf  = (const float*)d_in[5];
    const float* bff = (const float*)d_in[6];
    unsigned short* wsw = (unsigned short*)d_ws;   // 4 x 65536 bf16 = 512 KB
    float* o = (float*)d_out;

    hipLaunchKernelGGL(swizzle_w_kernel, dim3(128), dim3(256), 0, stream, Wq, Wk, Wv, Wf, wsw);
    hipLaunchKernelGGL(fused_node_kernel, dim3(4096), dim3(256), 0, stream, x, pos, wsw, bff, o);
}

// Round 2
// 709.573 us; speedup vs baseline: 2.2799x; 2.2799x over previous
//
#include <hip/hip_runtime.h>

// Fused TemporalAttentionLayer for MI355X (gfx950), round 2.
// N=4096 nodes, T=64, D=256, H=16, dh=16. One node per block, 4 waves.
// Wave w owns output columns [64w, 64w+64) == heads 4w..4w+3.
//
// Round-2 structure: all transposes eliminated via operand-swapped MFMA.
//  - Q,K computed TRANSPOSED (mfma(w,h)) -> lane holds Q[t=lc][dh=4q+r] = score-frag.
//  - Scores computed TRANSPOSED (mfma(kf,qf)) -> lane holds P[t=lc][s=4q+r] = PV A-frag.
//  - V computed straight (mfma(h,w)) -> lane holds V[s=4q+r][dh=lc] = PV B-frag.
// Only LDS traffic: h staging and attn_out (both required for cross-wave sharing).

typedef __attribute__((ext_vector_type(4))) float f32x4;
typedef __attribute__((ext_vector_type(8))) short bf16x8;
typedef __attribute__((ext_vector_type(4))) short bf16x4;

__device__ __forceinline__ unsigned short f2b(float f) {
    union { float f; unsigned u; } v; v.f = f;
    unsigned r = v.u + 0x7fffu + ((v.u >> 16) & 1u);   // RNE
    return (unsigned short)(r >> 16);
}
__device__ __forceinline__ float b2f(unsigned short s) {
    union { unsigned u; float f; } v; v.u = ((unsigned)s) << 16; return v.f;
}

// ---- preprocess: cast fp32 weights [K=256][N=256] to bf16 in MFMA frag order.
// Layout: [ntile(16)][kstep(8)][lane(64)][j(8)],
// element = W[ks*32+(lane>>4)*8+j][nt*16+(lane&15)].
// Serves as B-frag of W (straight GEMM) AND A-frag of W^T (transposed GEMM).
__global__ void swizzle_w_kernel(const float* __restrict__ Wq,
                                 const float* __restrict__ Wk,
                                 const float* __restrict__ Wv,
                                 const float* __restrict__ Wf,
                                 unsigned short* __restrict__ ws) {
    int tid  = blockIdx.x * 256 + threadIdx.x;   // 0..32767
    int mat  = tid >> 13;
    int rem  = tid & 8191;
    int nt   = rem >> 9;
    int ks   = (rem >> 6) & 7;
    int lane = rem & 63;
    const float* W = (mat == 0) ? Wq : (mat == 1) ? Wk : (mat == 2) ? Wv : Wf;
    int n  = nt * 16 + (lane & 15);
    int k0 = ks * 32 + (lane >> 4) * 8;
    bf16x8 o;
#pragma unroll
    for (int j = 0; j < 8; ++j) o[j] = (short)f2b(W[(k0 + j) * 256 + n]);
    *(bf16x8*)(ws + (size_t)mat * 65536 + (size_t)rem * 8) = o;
}

__global__ __launch_bounds__(256, 2) void fused_node_kernel(
    const float* __restrict__ x, const float* __restrict__ pos,
    const unsigned short* __restrict__ wsw, const float* __restrict__ bff,
    float* __restrict__ out)
{
    __shared__ unsigned short lds_h[64 * 264];   // h, later attn_out (bf16, pad 8)

    const int tid  = threadIdx.x;
    const int w    = tid >> 6;
    const int lane = tid & 63;
    const int quad = lane >> 4;
    const int lc   = lane & 15;
    const int node = blockIdx.x;

    // ---- stage 1: h = x + pos_emb  -> bf16 LDS
    {
        const float4* xv = (const float4*)(x + (size_t)node * 16384);
        const float4* pv = (const float4*)pos;
#pragma unroll
        for (int it = 0; it < 16; ++it) {
            int idx = it * 256 + tid;           // 4096 float4 chunks
            float4 a = xv[idx];
            float4 b = pv[idx];
            int row = idx >> 6, c4 = idx & 63;
            ushort4 o;
            o.x = f2b(a.x + b.x); o.y = f2b(a.y + b.y);
            o.z = f2b(a.z + b.z); o.w = f2b(a.w + b.w);
            *(ushort4*)&lds_h[row * 264 + c4 * 4] = o;
        }
    }
    __syncthreads();

    const f32x4 fzero = {0.f, 0.f, 0.f, 0.f};

    // fragment base pointers for this wave (ntile chunk = w*4 .. w*4+3)
    const unsigned short* wq_b = wsw;
    const unsigned short* wk_b = wsw + 65536;
    const unsigned short* wv_b = wsw + 131072;
    const unsigned short* wf_b = wsw + 196608;
#define WFRAG(base, mt, ks) (*(const bf16x8*)((base) + (size_t)(((w * 4 + (mt)) * 8 + (ks)) * 64 + lane) * 8))
#define HFRAG(j, ks) (*(const bf16x8*)&lds_h[(16 * (j) + lc) * 264 + (ks) * 32 + quad * 8])

    // ---- fused Q^T / K^T GEMM: aq[mt=dtile][nt=ttile] = mfma(Wq^T-frag, h^T-frag)
    f32x4 aq[4][4], ak[4][4];
#pragma unroll
    for (int i = 0; i < 4; ++i)
#pragma unroll
        for (int j = 0; j < 4; ++j) { aq[i][j] = fzero; ak[i][j] = fzero; }
#pragma unroll
    for (int ks = 0; ks < 8; ++ks) {
        bf16x8 hf[4];
#pragma unroll
        for (int j = 0; j < 4; ++j) hf[j] = HFRAG(j, ks);
#pragma unroll
        for (int mt = 0; mt < 4; ++mt) {
            bf16x8 wfq = WFRAG(wq_b, mt, ks);
            bf16x8 wfk = WFRAG(wk_b, mt, ks);
#pragma unroll
            for (int j = 0; j < 4; ++j) {
                aq[mt][j] = __builtin_amdgcn_mfma_f32_16x16x32_bf16(wfq, hf[j], aq[mt][j], 0, 0, 0);
                ak[mt][j] = __builtin_amdgcn_mfma_f32_16x16x32_bf16(wfk, hf[j], ak[mt][j], 0, 0, 0);
            }
        }
    }
    // lane now holds Q[t=16*nt+lc][dh=4*quad+r] for head (4w+mt) — pack to bf16
    bf16x4 qf[4][4], kf[4][4];   // [head][ttile]
#pragma unroll
    for (int mt = 0; mt < 4; ++mt)
#pragma unroll
        for (int j = 0; j < 4; ++j)
#pragma unroll
            for (int r = 0; r < 4; ++r) {
                qf[mt][j][r] = (short)f2b(aq[mt][j][r]);
                kf[mt][j][r] = (short)f2b(ak[mt][j][r]);
            }

    // ---- V GEMM (straight): av[i=stile][jn=headtile] = mfma(h-frag, Wv-frag)
    f32x4 av[4][4];
#pragma unroll
    for (int i = 0; i < 4; ++i)
#pragma unroll
        for (int j = 0; j < 4; ++j) av[i][j] = fzero;
#pragma unroll
    for (int ks = 0; ks < 8; ++ks) {
        bf16x8 hf[4];
#pragma unroll
        for (int i = 0; i < 4; ++i) hf[i] = HFRAG(i, ks);
#pragma unroll
        for (int jn = 0; jn < 4; ++jn) {
            bf16x8 wfv = WFRAG(wv_b, jn, ks);
#pragma unroll
            for (int i = 0; i < 4; ++i)
                av[i][jn] = __builtin_amdgcn_mfma_f32_16x16x32_bf16(hf[i], wfv, av[i][jn], 0, 0, 0);
        }
    }
    // lane holds V[s=16i+4quad+r][dh=lc] for head jn — already the PV B-frag
    bf16x4 vf[4][4];   // [head][stile]
#pragma unroll
    for (int i = 0; i < 4; ++i)
#pragma unroll
        for (int jn = 0; jn < 4; ++jn)
#pragma unroll
            for (int r = 0; r < 4; ++r)
                vf[jn][i][r] = (short)f2b(av[i][jn][r]);

    __syncthreads();   // all lds_h (h) reads done; it now becomes attn_out

    // ---- attention: 4 heads per wave, fully in-register
#pragma unroll
    for (int h = 0; h < 4; ++h) {
        // scores TRANSPOSED: st[js=stile][i=ttile]; lane holds S[t=16i+lc][s=16js+4quad+r]
        f32x4 st[4][4];
#pragma unroll
        for (int js = 0; js < 4; ++js)
#pragma unroll
            for (int i = 0; i < 4; ++i)
                st[js][i] = __builtin_amdgcn_mfma_f32_16x16x16bf16_1k(kf[h][js], qf[h][i], fzero, 0, 0, 0);

        // mask + exp + row-sum (row t = 16i+lc lives in this lane + 3 quad-siblings)
#pragma unroll
        for (int i = 0; i < 4; ++i) {
            const int t = 16 * i + lc;
            float sum = 0.f;
#pragma unroll
            for (int js = 0; js < 4; ++js)
#pragma unroll
                for (int r = 0; r < 4; ++r) {
                    int s = 16 * js + 4 * quad + r;
                    float p = (s <= t) ? __expf(st[js][i][r] * 0.125f) : 0.0f;
                    st[js][i][r] = p;
                    sum += p;
                }
            sum += __shfl_xor(sum, 16, 64);
            sum += __shfl_xor(sum, 32, 64);
            float rinv = 1.0f / sum;
#pragma unroll
            for (int js = 0; js < 4; ++js)
#pragma unroll
                for (int r = 0; r < 4; ++r) st[js][i][r] *= rinv;
        }

        // PV: P frags are st (already A-layout); V frags in regs
#pragma unroll
        for (int i = 0; i < 4; ++i) {
            f32x4 O = fzero;
#pragma unroll
            for (int js = 0; js < 4; ++js) {
                bf16x4 pa;
#pragma unroll
                for (int r = 0; r < 4; ++r) pa[r] = (short)f2b(st[js][i][r]);
                O = __builtin_amdgcn_mfma_f32_16x16x16bf16_1k(pa, vf[h][js], O, 0, 0, 0);
            }
            // O lane holds attn_out[t=16i+4quad+r][dh=lc] — write to lds_h
#pragma unroll
            for (int r = 0; r < 4; ++r)
                lds_h[(16 * i + 4 * quad + r) * 264 + w * 64 + h * 16 + lc] = f2b(O[r]);
        }
    }

    __syncthreads();   // attn_out complete across waves

    // ---- FFN (straight): af[i][jn] = attn_out @ Wff
    f32x4 af[4][4];
#pragma unroll
    for (int i = 0; i < 4; ++i)
#pragma unroll
        for (int j = 0; j < 4; ++j) af[i][j] = fzero;
#pragma unroll
    for (int ks = 0; ks < 8; ++ks) {
        bf16x8 hf[4];
#pragma unroll
        for (int i = 0; i < 4; ++i) hf[i] = HFRAG(i, ks);
#pragma unroll
        for (int jn = 0; jn < 4; ++jn) {
            bf16x8 wff = WFRAG(wf_b, jn, ks);
#pragma unroll
            for (int i = 0; i < 4; ++i)
                af[i][jn] = __builtin_amdgcn_mfma_f32_16x16x32_bf16(hf[i], wff, af[i][jn], 0, 0, 0);
        }
    }
    {
        float bias[4];
#pragma unroll
        for (int jn = 0; jn < 4; ++jn) bias[jn] = bff[w * 64 + jn * 16 + lc];
        float* outn = out + (size_t)node * 16384;
#pragma unroll
        for (int i = 0; i < 4; ++i)
#pragma unroll
            for (int jn = 0; jn < 4; ++jn)
#pragma unroll
                for (int r = 0; r < 4; ++r) {
                    int row = i * 16 + quad * 4 + r;
                    int col = w * 64 + jn * 16 + lc;
                    float v = af[i][jn][r] + bias[jn];
                    v = fmaxf(v, 0.0f);
                    v += b2f(lds_h[row * 264 + col]);
                    outn[row * 256 + col] = v;
                }
    }
#undef WFRAG
#undef HFRAG
}

extern "C" void kernel_launch(void* const* d_in, const int* in_sizes, int n_in,
                              void* d_out, int out_size, void* d_ws, size_t ws_size,
                              hipStream_t stream) {
    const float* x   = (const float*)d_in[0];
    const float* pos = (const float*)d_in[1];
    const float* Wq  = (const float*)d_in[2];
    const float* Wk  = (const float*)d_in[3];
    const float* Wv  = (const float*)d_in[4];
    const float* Wf  = (const float*)d_in[5];
    const float* bff = (const float*)d_in[6];
    unsigned short* wsw = (unsigned short*)d_ws;   // 4 x 65536 bf16 = 512 KB
    float* o = (float*)d_out;

    hipLaunchKernelGGL(swizzle_w_kernel, dim3(128), dim3(256), 0, stream, Wq, Wk, Wv, Wf, wsw);
    hipLaunchKernelGGL(fused_node_kernel, dim3(4096), dim3(256), 0, stream, x, pos, wsw, bff, o);
}